// Round 20
// baseline (182.385 us; speedup 1.0000x reference)
//
#include <hip/hip_runtime.h>
#include <hip/hip_fp16.h>

// NCN producer/consumer pairs + SPECULATIVE SEGMENTED SCAN (R18 + race fix).
// Chains (b,h,c) = 1024 pairs {gemm wave, scan wave}. The scan step map
// contracts (|dy'/dy| <= 0.5), so each 32-step chunk runs speculatively from
// init 0 (steps >=16 correct to 1.5e-5, end to 5e-10); steps 0..15 re-run
// (fixup) from the true init = previous chunk's spec end. 4 spec + 4 fixup
// chains interleave per wave -> 8 independent dep chains hide the per-step
// transcendental latency that capped R15-R17 at ~136us.
// MX ring: 8 packed 4KB slots; slot(G) = G&7 is read TWICE (spec batch n,
// fixup batch n+1) -> consumer signals fsl = 4n ("chunks <= 4n-1 consumed")
// at batch n's preload, AFTER the fixup re-read (lgkm-drained). R18's bug
// was signaling 4n+4, letting the producer overwrite fixup slots.
// 512-thread blocks (4 pairs), launch_bounds(512,2) -> 256-VGPR budget (the
// consumer's 96 mix VGPRs would spill under a 128 cap). LDS 144KB/block.
// y handoff f16 in d_ws; module 3 writes f32 directly to d_out. Fallback
// small-ws: f16 in d_out first-halves + expand. MFMA mapping = R8-validated.

typedef _Float16 f16;
typedef _Float16 half8 __attribute__((ext_vector_type(8)));
typedef float f32x4 __attribute__((ext_vector_type(4)));
typedef unsigned uint4v __attribute__((ext_vector_type(4)));

constexpr int B = 8, T = 4096, D = 1024, H = 16, DH = 64, NC = 8, NM = 4;
constexpr int KS = 32;               // steps per chunk
constexpr int NG = 64;               // total chunks (4 modules x 16)
constexpr size_t YWS_BYTES = (size_t)B * T * 2048;   // 64 MiB
constexpr float L2E = 1.44269504088896340736f;

__device__ __forceinline__ float exp2_fast(float v) {
  float r;
  asm("v_exp_f32 %0, %1" : "=v"(r) : "v"(v));
  return r;
}

template <bool WS>
__global__ __launch_bounds__(512, 2)
void ncn_spec(const float* __restrict__ x, const float* __restrict__ xa,
              const float* __restrict__ w, float* __restrict__ out,
              unsigned char* __restrict__ ybuf) {
  constexpr int YROW = WS ? 2048 : 4096;
  __shared__ __align__(16) unsigned char YST[4][4096];      // per-pair staged
  __shared__ __align__(16) unsigned char MXS[4][8][4096];   // per-pair ring-8
  __shared__ int FLG[4][4];            // {fgp, fsl, ffn, pad}

  const int tid = threadIdx.x, lane = tid & 63, wv = tid >> 6;
  const int pair = wv >> 1;
  const bool gemmw = (wv & 1) == 0;
  const int g = blockIdx.x * 4 + pair;       // chain id 0..1023
  const int c = g & 7, h = (g >> 3) & 15, b = g >> 7;
  const int lr = lane & 15, lg = lane >> 4;

  const unsigned char* const xb = (const unsigned char*)x + (size_t)b * T * 4096;
  unsigned char* const ob = (unsigned char*)out + (size_t)b * T * 4096;
  unsigned char* const yb = ybuf + (size_t)b * T * YROW;

  if (tid < 16) ((int*)FLG)[tid] = 0;
  __syncthreads();                           // only barrier (flag init)

  int* const fgp = &FLG[pair][0];
  int* const fsl = &FLG[pair][1];
  int* const ffn = &FLG[pair][2];

  auto waitge = [&](int* f, int v) {
    while (__hip_atomic_load(f, __ATOMIC_ACQUIRE,
                             __HIP_MEMORY_SCOPE_WORKGROUP) < v)
      __builtin_amdgcn_s_sleep(1);
  };
  auto signal = [&](int* f, int v) {
    if (lane == 0)
      __hip_atomic_store(f, v, __ATOMIC_RELEASE, __HIP_MEMORY_SCOPE_WORKGROUP);
  };

  if (gemmw) {
    // =========== producer: prefetch -> stage -> MFMA -> packed MX ===========
    unsigned char* const yst = YST[pair];
    uint4v pf[8];
    half8 Wf[4][2];

    auto prefetch = [&](int Gn) {
      if (Gn >= NG) return;
      const int m = Gn >> 4, ch = Gn & 15;
      if (m >= 1) waitge(ffn, Gn - 15);      // chunk Gn-16's y final
      const int J0 = ch * KS;
      if (m == 0) {
#pragma unroll
        for (int i = 0; i < 8; ++i) {
          const int lt = i * 4 + (lane >> 4);
          const int t = (J0 + lt) * 8 + c;
          pf[i] = *(const uint4v*)(xb + (size_t)t * 4096 + h * 256 +
                                   (lane & 15) * 16);
        }
      } else {
#pragma unroll
        for (int i = 0; i < 4; ++i) {
          const int lt = i * 8 + (lane >> 3);
          const int t = (J0 + lt) * 8 + c;
          pf[i] = *(const uint4v*)(yb + (size_t)t * YROW + h * 128 +
                                   (lane & 7) * 16);
        }
      }
    };
    auto stage = [&](int m) {
      if (m == 0) {
#pragma unroll
        for (int i = 0; i < 8; ++i) {
          const int lt = i * 4 + (lane >> 4);
          const f32x4 v = __builtin_bit_cast(f32x4, pf[i]);
          const __half2 p0 = __floats2half2_rn(v.x, v.y);
          const __half2 p1 = __floats2half2_rn(v.z, v.w);
          uint2 pk;
          pk.x = __builtin_bit_cast(unsigned, p0);
          pk.y = __builtin_bit_cast(unsigned, p1);
          *(uint2*)(yst + lt * 128 + (((lane & 15) * 8) ^ ((lt & 7) << 4))) = pk;
        }
      } else {
#pragma unroll
        for (int i = 0; i < 4; ++i) {
          const int lt = i * 8 + (lane >> 3);
          *(uint4v*)(yst + lt * 128 + (((lane & 7) * 16) ^ ((lt & 7) << 4))) =
              pf[i];
        }
      }
    };

    prefetch(0);
    for (int G = 0; G < NG; ++G) {
      const int m = G >> 4;
      if ((G & 15) == 0) {                   // W frags (R8-validated mapping)
        const float* wh = w + ((size_t)m * H + h) * DH * DH;
#pragma unroll
        for (int it = 0; it < 4; ++it)
#pragma unroll
          for (int kt = 0; kt < 2; ++kt)
#pragma unroll
            for (int j = 0; j < 8; ++j)
              Wf[it][kt][j] =
                  (f16)wh[(size_t)(kt * 32 + lg * 8 + j) * DH + it * 16 + lr];
      }
      stage(m);
      prefetch(G + 1);

      f32x4 acc[2][4];
#pragma unroll
      for (int tq = 0; tq < 2; ++tq) {
        half8 Xf[2];
#pragma unroll
        for (int kt = 0; kt < 2; ++kt) {
          const int lt = tq * 16 + lr;
          Xf[kt] = *(const half8*)(yst + lt * 128 +
                                   ((kt * 64 + lg * 16) ^ ((lt & 7) << 4)));
        }
#pragma unroll
        for (int it = 0; it < 4; ++it) acc[tq][it] = (f32x4){0.f, 0.f, 0.f, 0.f};
#pragma unroll
        for (int kt = 0; kt < 2; ++kt)
#pragma unroll
          for (int it = 0; it < 4; ++it)
            acc[tq][it] = __builtin_amdgcn_mfma_f32_16x16x32_f16(
                Xf[kt], Wf[it][kt], acc[tq][it], 0, 0, 0);
      }

      waitge(fsl, G - 7);                    // ring slot G&7 truly free
      unsigned char* const mxs = &MXS[pair][G & 7][0];
      // packed scatter: step k = tq*16+lg*4+j at e = it*16+lr
      // byte = (tq*2+(lg>>1))*1024 + e*16 + (lg&1)*8  (uint2 covers j=0..3)
#pragma unroll
      for (int tq = 0; tq < 2; ++tq)
#pragma unroll
        for (int it = 0; it < 4; ++it) {
          const int e = it * 16 + lr;
          const __half2 p0 = __floats2half2_rn(acc[tq][it].x, acc[tq][it].y);
          const __half2 p1 = __floats2half2_rn(acc[tq][it].z, acc[tq][it].w);
          uint2 pk;
          pk.x = __builtin_bit_cast(unsigned, p0);
          pk.y = __builtin_bit_cast(unsigned, p1);
          *(uint2*)(mxs + (tq * 2 + (lg >> 1)) * 1024 + e * 16 + (lg & 1) * 8) =
              pk;
        }
      asm volatile("s_waitcnt lgkmcnt(0)" ::: "memory");
      signal(fgp, G + 1);
    }
  } else {
    // =========== consumer: batched spec (4) + riding fixup (4) ===========
    float carry = xa[((size_t)b * NC + c) * D + h * DH + lane];  // true init
    float endv[4] = {0.f, 0.f, 0.f, 0.f};
    const unsigned char* const mxp = &MXS[pair][0][0];

    auto step = [&](float& yv, float mv) {
      const float z = fmaf(yv, L2E, mv);     // (y + m) * log2e
      const float E = exp2_fast(z);
      const float r = __builtin_amdgcn_rcpf(E + 1.0f);
      yv = fmaf(r, -2.0f, 1.0f);             // tanh(0.5(y+m))
    };

    for (int n = 0; n < 16; ++n) {
      const int msp = n >> 2;                // spec module
      const int mfx = (n - 1) >> 2;          // fixup module (n>=1)
      waitge(fgp, 4 * n + 4);

      // preload ALL mix: spec chunks 4n..4n+3 (full), fixup 4n-4..4n-1 (k<16)
      half8 ms[4][4], mf[4][2];
#pragma unroll
      for (int j = 0; j < 4; ++j) {
        const unsigned char* sb = mxp + ((4 * n + j) & 7) * 4096 + lane * 16;
#pragma unroll
        for (int gq = 0; gq < 4; ++gq)
          ms[j][gq] = *(const half8*)(sb + gq * 1024);
      }
      if (n >= 1) {
#pragma unroll
        for (int j = 0; j < 4; ++j) {
          const unsigned char* sb =
              mxp + ((4 * (n - 1) + j) & 7) * 4096 + lane * 16;
#pragma unroll
          for (int gq = 0; gq < 2; ++gq)
            mf[j][gq] = *(const half8*)(sb + gq * 1024);
        }
      }
      asm volatile("s_waitcnt lgkmcnt(0)" ::: "memory");
      // RACE FIX (R18): chunks <= 4n-1 are now fully consumed (their fixup
      // re-read just drained). Producer may reuse their slots only now.
      signal(fsl, 4 * n);

      unsigned char* sps[4];
      unsigned char* spf[4];
#pragma unroll
      for (int j = 0; j < 4; ++j) {
        const int chs = (4 * n + j) & 15;
        const int tq0 = chs * 256 + 128 + c;             // t at k=16
        sps[j] = (WS && msp == 3)
                     ? ob + (size_t)tq0 * 4096 + h * 256 + 4 * lane
                     : yb + (size_t)tq0 * YROW + h * 128 + 2 * lane;
        if (n >= 1) {
          const int chf = (4 * (n - 1) + j) & 15;
          const int tf0 = chf * 256 + c;                 // t at k=0
          spf[j] = (WS && mfx == 3)
                       ? ob + (size_t)tf0 * 4096 + h * 256 + 4 * lane
                       : yb + (size_t)tf0 * YROW + h * 128 + 2 * lane;
        }
      }
      const size_t strdS = (WS && msp == 3) ? (size_t)8 * 4096 : (size_t)8 * YROW;
      const size_t strdF = (WS && mfx == 3) ? (size_t)8 * 4096 : (size_t)8 * YROW;

      float ysp[4] = {0.f, 0.f, 0.f, 0.f};   // spec ALWAYS starts from 0
      float yfx[4];
      if (n >= 1) {
        yfx[0] = carry;                      // end of chunk 4(n-1)-1
        yfx[1] = endv[0];
        yfx[2] = endv[1];
        yfx[3] = endv[2];
        carry = endv[3];                     // init for NEXT batch's fixup[0]
      }

#pragma unroll
      for (int k = 0; k < KS; ++k) {
#pragma unroll
        for (int j = 0; j < 4; ++j) {        // 4 spec chains
          const float mv = (float)ms[j][k >> 3][k & 7] * L2E;
          step(ysp[j], mv);
          if (k >= 16) {
            if (WS && msp == 3) *(float*)sps[j] = ysp[j];
            else *(__half*)sps[j] = __float2half_rn(ysp[j]);
            sps[j] += strdS;
          }
        }
        if (k < 16 && n >= 1) {
#pragma unroll
          for (int j = 0; j < 4; ++j) {      // 4 fixup chains (prev batch)
            const float mv = (float)mf[j][k >> 3][k & 7] * L2E;
            step(yfx[j], mv);
            if (WS && mfx == 3) *(float*)spf[j] = yfx[j];
            else *(__half*)spf[j] = __float2half_rn(yfx[j]);
            spf[j] += strdF;
          }
        }
      }
#pragma unroll
      for (int j = 0; j < 4; ++j) endv[j] = ysp[j];

      asm volatile("s_waitcnt vmcnt(0)" ::: "memory");
      signal(ffn, 4 * n);                    // chunks <= 4n-1 fully final
    }

    // tail: fixup of chunks 60..63 (module 3)
    {
      half8 mf[4][2];
#pragma unroll
      for (int j = 0; j < 4; ++j) {
        const unsigned char* sb = mxp + ((60 + j) & 7) * 4096 + lane * 16;
#pragma unroll
        for (int gq = 0; gq < 2; ++gq)
          mf[j][gq] = *(const half8*)(sb + gq * 1024);
      }
      asm volatile("s_waitcnt lgkmcnt(0)" ::: "memory");
      unsigned char* spf[4];
#pragma unroll
      for (int j = 0; j < 4; ++j) {
        const int tf0 = ((60 + j) & 15) * 256 + c;
        spf[j] = WS ? ob + (size_t)tf0 * 4096 + h * 256 + 4 * lane
                    : yb + (size_t)tf0 * YROW + h * 128 + 2 * lane;
      }
      const size_t strd = WS ? (size_t)8 * 4096 : (size_t)8 * YROW;
      float yfx[4];
      yfx[0] = carry; yfx[1] = endv[0]; yfx[2] = endv[1]; yfx[3] = endv[2];
#pragma unroll
      for (int k = 0; k < 16; ++k)
#pragma unroll
        for (int j = 0; j < 4; ++j) {
          const float mv = (float)mf[j][k >> 3][k & 7] * L2E;
          step(yfx[j], mv);
          if (WS) *(float*)spf[j] = yfx[j];
          else *(__half*)spf[j] = __float2half_rn(yfx[j]);
          spf[j] += strd;
        }
      asm volatile("s_waitcnt vmcnt(0)" ::: "memory");
    }

    float* ya = out + (size_t)B * T * D;
    ya[((size_t)b * NC + c) * D + h * DH + lane] = endv[3];
  }
}

// ---- expand (fallback path): y f16 (first 2KB of row) -> f32 rows ----
__global__ __launch_bounds__(256)
void expand(float* __restrict__ buf) {
  typedef _Float16 half4v __attribute__((ext_vector_type(4)));
  __shared__ __align__(16) f16 rs[4 * 1024];
  const int tid = threadIdx.x;
  unsigned char* const base = (unsigned char*)buf + (size_t)blockIdx.x * 4 * 4096;
#pragma unroll
  for (int p = 0; p < 2; ++p) {
    const int gid = p * 256 + tid;
    const int row = gid >> 7, c16 = gid & 127;
    *(uint4v*)((unsigned char*)rs + row * 2048 + c16 * 16) =
        *(const uint4v*)(base + (size_t)row * 4096 + c16 * 16);
  }
  __syncthreads();
#pragma unroll
  for (int p = 0; p < 4; ++p) {
    const int gid = p * 256 + tid;
    const int row = gid >> 8, c4 = gid & 255;
    const half4v hv = *(const half4v*)((unsigned char*)rs + row * 2048 + c4 * 8);
    f32x4 v;
#pragma unroll
    for (int e = 0; e < 4; ++e) v[e] = (float)hv[e];
    *(f32x4*)(base + (size_t)row * 4096 + c4 * 16) = v;
  }
}

extern "C" void kernel_launch(void* const* d_in, const int* in_sizes, int n_in,
                              void* d_out, int out_size, void* d_ws, size_t ws_size,
                              hipStream_t stream) {
  (void)in_sizes; (void)n_in; (void)out_size;
  const float* x  = (const float*)d_in[0];
  const float* xa = (const float*)d_in[1];
  const float* w  = (const float*)d_in[2];
  float* out = (float*)d_out;

  const bool usews = (d_ws != nullptr) && (ws_size >= YWS_BYTES);
  if (usews) {
    hipLaunchKernelGGL((ncn_spec<true>), dim3(256), dim3(512), 0, stream,
                       x, xa, w, out, (unsigned char*)d_ws);
  } else {
    hipLaunchKernelGGL((ncn_spec<false>), dim3(256), dim3(512), 0, stream,
                       x, xa, w, out, (unsigned char*)out);
    hipLaunchKernelGGL(expand, dim3(B * T / 4), dim3(256), 0, stream, out);
  }
}